// Round 1
// baseline (1048.579 us; speedup 1.0000x reference)
//
#include <hip/hip_runtime.h>
#include <hip/hip_bf16.h>

// Problem constants: B=4, T=2048, E=8, C=1024, I=2048. M = B*T = 8192.
// Outputs: agg [8192,1024] fp32, experts_out [8192,8,1024] fp32, concat in d_out.

typedef unsigned short u16;
typedef __bf16 v8bf __attribute__((ext_vector_type(8)));
typedef float  v4f  __attribute__((ext_vector_type(4)));

#define M_TOT 8192
#define E_DIM 8
#define C_DIM 1024
#define I_DIM 2048

__device__ inline u16 f2b(float f) {
    __hip_bfloat16 h = __float2bfloat16(f);
    return *reinterpret_cast<u16*>(&h);
}

// tanh-form GELU: max |diff vs exact-erf gelu| ~3e-3, NaN-safe at |x| large.
__device__ inline float fast_gelu(float x) {
    float x2 = x * x;
    float z  = x * fmaf(0.0356774081f, x2, 0.7978845608f);
    float u  = __expf(2.0f * z);
    float th = fmaf(-2.0f, __builtin_amdgcn_rcpf(u + 1.0f), 1.0f);
    return 0.5f * x * (1.0f + th);
}

// async global->LDS, 16B per lane; LDS dest = wave-uniform base + lane*16
__device__ inline void gload16(const u16* g, u16* l) {
    __builtin_amdgcn_global_load_lds(
        (const __attribute__((address_space(1))) void*)g,
        (__attribute__((address_space(3))) void*)l,
        16, 0, 0);
}

// ---------------- pass 0: conversions ----------------

__global__ __launch_bounds__(256) void cvt_x_kernel(const float* __restrict__ x,
                                                    u16* __restrict__ xb) {
    int idx = blockIdx.x * 256 + threadIdx.x;   // each thread: 4 floats
    float4 v = reinterpret_cast<const float4*>(x)[idx];
    ushort4 o;
    o.x = f2b(v.x); o.y = f2b(v.y); o.z = f2b(v.z); o.w = f2b(v.w);
    reinterpret_cast<ushort4*>(xb)[idx] = o;
}

// in: (E, R, Cd) fp32 row-major  ->  out: (E, Cd, R) bf16
__global__ __launch_bounds__(256) void transpose_cvt_kernel(const float* __restrict__ in,
                                                            u16* __restrict__ out,
                                                            int R, int Cd) {
    __shared__ float tile[32][33];
    int e = blockIdx.z;
    const float* ip = in + (size_t)e * R * Cd;
    u16* op = out + (size_t)e * R * Cd;
    int c0 = blockIdx.x * 32, r0 = blockIdx.y * 32;
    int tx = threadIdx.x & 31;
    int ty = threadIdx.x >> 5;   // 0..7
#pragma unroll
    for (int k = 0; k < 4; k++)
        tile[ty + 8 * k][tx] = ip[(size_t)(r0 + ty + 8 * k) * Cd + c0 + tx];
    __syncthreads();
#pragma unroll
    for (int k = 0; k < 4; k++)
        op[(size_t)(c0 + ty + 8 * k) * R + r0 + tx] = f2b(tile[tx][ty + 8 * k]);
}

// ---------------- 256x256 ring-4 counted-vmcnt GEMM core ----------------
// A: M x K bf16 row-major (k-contig). Bt: N x K bf16 row-major (k-contig).
// 512 threads = 8 waves (2M x 4N), per-wave output 128x64 = acc[8][4] 16x16 frags.
// LDS: per operand, ring of 4 slots of [256 rows][32 k] bf16 (16 KiB each).
// Slot for k-slice s = s&3. Phase s: read slice s, stage slice s+3 (slot of
// slice s-1, whose reads drained before the phase-(s-1) end barrier), 32 MFMA,
// vmcnt(8) (2 slices in flight, never 0), one s_barrier.
// Swizzle (involution, applied both sides): byte ^= ((byte>>7)&3)<<4 within a
// 16KiB slot. global_load_lds writes linearly; the per-lane GLOBAL source is
// inverse-swizzled, ds_read uses the swizzled address (rule 21).
template<int K>
__device__ inline void gemm_core(const u16* __restrict__ A, const u16* __restrict__ Bt,
                                 u16* ldsA, u16* ldsB, int m0, int n0, v4f (&acc)[8][4]) {
    constexpr int NS = K / 32;
    const int t = threadIdx.x, w = t >> 6, l = t & 63;
    const int wm = w >> 2, wn = w & 3;

    // staging precompute: linear LDS dest f -> logical g -> global (row, col)
    const u16* asrc[2]; const u16* bsrc[2]; int adst[2];
#pragma unroll
    for (int u = 0; u < 2; ++u) {
        int f = u * 8192 + w * 1024 + l * 16;        // dest byte offset in slot
        int g = f ^ (((f >> 7) & 3) << 4);           // logical byte offset
        int row = g >> 6, col = (g >> 1) & 31;       // 64B rows, elem col (x8 aligned)
        asrc[u] = A  + (size_t)(m0 + row) * K + col;
        bsrc[u] = Bt + (size_t)(n0 + row) * K + col;
        adst[u] = u * 4096 + w * 512;                // wave-uniform elem offset
    }

    // fragment LDS element offsets (swizzled), constant through the loop
    const int lr = l & 15, lk = l >> 4;
    int aoffE[8], boffE[4];
#pragma unroll
    for (int i = 0; i < 8; ++i) {
        int g = (wm * 128 + i * 16 + lr) * 64 + lk * 16;
        aoffE[i] = (g ^ (((g >> 7) & 3) << 4)) >> 1;
    }
#pragma unroll
    for (int j = 0; j < 4; ++j) {
        int g = (wn * 64 + j * 16 + lr) * 64 + lk * 16;
        boffE[j] = (g ^ (((g >> 7) & 3) << 4)) >> 1;
    }

    auto STAGE = [&](int ks) {
        u16* la = ldsA + (ks & 3) * 8192;
        u16* lb = ldsB + (ks & 3) * 8192;
        int ko = ks * 32;
        gload16(asrc[0] + ko, la + adst[0]);
        gload16(asrc[1] + ko, la + adst[1]);
        gload16(bsrc[0] + ko, lb + adst[0]);
        gload16(bsrc[1] + ko, lb + adst[1]);
    };

#pragma unroll
    for (int i = 0; i < 8; ++i)
#pragma unroll
        for (int j = 0; j < 4; ++j) acc[i][j] = (v4f){0.f, 0.f, 0.f, 0.f};

    // prologue: slices 0,1,2 in flight; land slice 0 (12 issued -> wait to 8)
    STAGE(0); STAGE(1); STAGE(2);
    asm volatile("s_waitcnt vmcnt(8)" ::: "memory");
    __builtin_amdgcn_s_barrier();

    for (int s = 0; s < NS; ++s) {
        const u16* as = ldsA + (s & 3) * 8192;
        const u16* bs = ldsB + (s & 3) * 8192;
        v8bf af[8], bfr[4];
#pragma unroll
        for (int i = 0; i < 8; ++i) af[i] = *(const v8bf*)(as + aoffE[i]);
#pragma unroll
        for (int j = 0; j < 4; ++j) bfr[j] = *(const v8bf*)(bs + boffE[j]);
        if (s < NS - 3) STAGE(s + 3);
        __builtin_amdgcn_s_setprio(1);
#pragma unroll
        for (int i = 0; i < 8; ++i)
#pragma unroll
            for (int j = 0; j < 4; ++j)
                acc[i][j] = __builtin_amdgcn_mfma_f32_16x16x32_bf16(af[i], bfr[j], acc[i][j], 0, 0, 0);
        __builtin_amdgcn_s_setprio(0);
        // counted drains: slice s+1 must have landed before the barrier.
        if (s < NS - 3)       asm volatile("s_waitcnt vmcnt(8)" ::: "memory");
        else if (s == NS - 3) asm volatile("s_waitcnt vmcnt(4)" ::: "memory");
        else if (s == NS - 2) asm volatile("s_waitcnt vmcnt(0)" ::: "memory");
        if (s < NS - 1) __builtin_amdgcn_s_barrier();
    }
}

// ---------------- GEMM1: h[e] = gelu(x @ w1[e]), bf16 out ----------------
__global__ __launch_bounds__(512, 2) void gemm1_kernel(const u16* __restrict__ A,
                                                       const u16* __restrict__ w1T,
                                                       u16* __restrict__ H,
                                                       int e_base, size_t h_stride) {
    __shared__ __align__(16) u16 lds[65536];   // 128 KiB: A ring 64K + B ring 64K
    int e = e_base + blockIdx.z;
    const u16* Bt = w1T + (size_t)e * I_DIM * C_DIM;
    u16* Hp = H + (size_t)blockIdx.z * h_stride;
    int m0 = blockIdx.y * 256, n0 = blockIdx.x * 256;

    v4f acc[8][4];
    gemm_core<C_DIM>(A, Bt, lds, lds + 32768, m0, n0, acc);

    int l = threadIdx.x & 63, w = threadIdx.x >> 6;
    int wm = w >> 2, wn = w & 3;
    int lr4 = (l >> 4) * 4, lc = l & 15;     // C/D: row=(lane>>4)*4+reg, col=lane&15
#pragma unroll
    for (int i = 0; i < 8; ++i) {
        int mg = m0 + wm * 128 + i * 16 + lr4;
#pragma unroll
        for (int j = 0; j < 4; ++j) {
            int ng = n0 + wn * 64 + j * 16 + lc;
#pragma unroll
            for (int r = 0; r < 4; ++r)
                Hp[(size_t)(mg + r) * I_DIM + ng] = f2b(fast_gelu(acc[i][j][r]));
        }
    }
}

// ---------------- GEMM2: eo[:,e,:] = h[e] @ w2[e], fp32 strided out ----------------
__global__ __launch_bounds__(512, 2) void gemm2_kernel(const u16* __restrict__ H,
                                                       const u16* __restrict__ w2T,
                                                       float* __restrict__ EO,
                                                       int e_base, size_t h_stride) {
    __shared__ __align__(16) u16 lds[65536];
    int e = e_base + blockIdx.z;
    const u16* A  = H + (size_t)blockIdx.z * h_stride;
    const u16* Bt = w2T + (size_t)e * C_DIM * I_DIM;
    int m0 = blockIdx.y * 256, n0 = blockIdx.x * 256;

    v4f acc[8][4];
    gemm_core<I_DIM>(A, Bt, lds, lds + 32768, m0, n0, acc);

    int l = threadIdx.x & 63, w = threadIdx.x >> 6;
    int wm = w >> 2, wn = w & 3;
    int lr4 = (l >> 4) * 4, lc = l & 15;
#pragma unroll
    for (int i = 0; i < 8; ++i) {
        int mg = m0 + wm * 128 + i * 16 + lr4;
#pragma unroll
        for (int j = 0; j < 4; ++j) {
            int ng = n0 + wn * 64 + j * 16 + lc;
#pragma unroll
            for (int r = 0; r < 4; ++r)
                EO[((size_t)(mg + r) * E_DIM + e) * C_DIM + ng] = acc[i][j][r];
        }
    }
}

// ---------------- combine: agg[m][c] = sum_e r[m][e] * eo[m][e][c] ----------------
__global__ __launch_bounds__(256) void combine_kernel(const float* __restrict__ EO,
                                                      const float* __restrict__ Rw,
                                                      float* __restrict__ agg) {
    int idx = blockIdx.x * 256 + threadIdx.x;
    int m = idx >> 8, cq = idx & 255;           // 256 float4 per row
    const float4* eo4 = reinterpret_cast<const float4*>(EO);
    float4 s = make_float4(0.f, 0.f, 0.f, 0.f);
#pragma unroll
    for (int e = 0; e < E_DIM; e++) {
        float r = Rw[m * E_DIM + e];
        float4 v = eo4[((size_t)m * E_DIM + e) * 256 + cq];
        s.x += r * v.x; s.y += r * v.y; s.z += r * v.z; s.w += r * v.w;
    }
    reinterpret_cast<float4*>(agg)[(size_t)m * 256 + cq] = s;
}

extern "C" void kernel_launch(void* const* d_in, const int* in_sizes, int n_in,
                              void* d_out, int out_size, void* d_ws, size_t ws_size,
                              hipStream_t stream) {
    const float* x  = (const float*)d_in[0];
    const float* rw = (const float*)d_in[1];
    const float* w1 = (const float*)d_in[2];
    const float* w2 = (const float*)d_in[3];

    float* agg = (float*)d_out;
    float* EO  = agg + (size_t)M_TOT * C_DIM;   // experts_out region

    // workspace layout (bf16 elements)
    u16* xb  = (u16*)d_ws;                              // 8192*1024
    u16* w1T = xb  + (size_t)M_TOT * C_DIM;             // 8*2048*1024  [e][i][c]
    u16* w2T = w1T + (size_t)E_DIM * I_DIM * C_DIM;     // 8*1024*2048  [e][c][i]
    u16* h   = w2T + (size_t)E_DIM * C_DIM * I_DIM;     // h region

    size_t elems_before_h = (size_t)M_TOT * C_DIM + 2 * (size_t)E_DIM * I_DIM * C_DIM;
    size_t h_per_expert   = (size_t)M_TOT * I_DIM;
    bool batched = ws_size >= (elems_before_h + (size_t)E_DIM * h_per_expert) * sizeof(u16);

    cvt_x_kernel<<<(M_TOT * C_DIM) / 1024, 256, 0, stream>>>(x, xb);
    transpose_cvt_kernel<<<dim3(I_DIM / 32, C_DIM / 32, E_DIM), 256, 0, stream>>>(w1, w1T, C_DIM, I_DIM);
    transpose_cvt_kernel<<<dim3(C_DIM / 32, I_DIM / 32, E_DIM), 256, 0, stream>>>(w2, w2T, I_DIM, C_DIM);

    if (batched) {
        gemm1_kernel<<<dim3(I_DIM / 256, M_TOT / 256, E_DIM), 512, 0, stream>>>(
            xb, w1T, h, 0, h_per_expert);
        gemm2_kernel<<<dim3(C_DIM / 256, M_TOT / 256, E_DIM), 512, 0, stream>>>(
            h, w2T, EO, 0, h_per_expert);
    } else {
        for (int e = 0; e < E_DIM; e++) {
            gemm1_kernel<<<dim3(I_DIM / 256, M_TOT / 256, 1), 512, 0, stream>>>(
                xb, w1T, h, e, 0);
            gemm2_kernel<<<dim3(C_DIM / 256, M_TOT / 256, 1), 512, 0, stream>>>(
                h, w2T, EO, e, 0);
        }
    }

    combine_kernel<<<M_TOT, 256, 0, stream>>>(EO, rw, agg);
}

// Round 2
// 1005.232 us; speedup vs baseline: 1.0431x; 1.0431x over previous
//
#include <hip/hip_runtime.h>
#include <hip/hip_bf16.h>

// Problem constants: B=4, T=2048, E=8, C=1024, I=2048. M = B*T = 8192.
// Outputs: agg [8192,1024] fp32, experts_out [8192,8,1024] fp32, concat in d_out.

typedef unsigned short u16;
typedef __bf16 v8bf __attribute__((ext_vector_type(8)));
typedef float  v4f  __attribute__((ext_vector_type(4)));

#define M_TOT 8192
#define E_DIM 8
#define C_DIM 1024
#define I_DIM 2048

__device__ inline u16 f2b(float f) {
    __hip_bfloat16 h = __float2bfloat16(f);
    return *reinterpret_cast<u16*>(&h);
}

// tanh-form GELU: max |diff vs exact-erf gelu| ~3e-3, NaN-safe at |x| large.
__device__ inline float fast_gelu(float x) {
    float x2 = x * x;
    float z  = x * fmaf(0.0356774081f, x2, 0.7978845608f);
    float u  = __expf(2.0f * z);
    float th = fmaf(-2.0f, __builtin_amdgcn_rcpf(u + 1.0f), 1.0f);
    return 0.5f * x * (1.0f + th);
}

// async global->LDS, 16B per lane; LDS dest = wave-uniform base + lane*16
__device__ inline void gload16(const u16* g, u16* l) {
    __builtin_amdgcn_global_load_lds(
        (const __attribute__((address_space(1))) void*)g,
        (__attribute__((address_space(3))) void*)l,
        16, 0, 0);
}

// ---------------- pass 0: conversions ----------------

__global__ __launch_bounds__(256) void cvt_x_kernel(const float* __restrict__ x,
                                                    u16* __restrict__ xb) {
    int idx = blockIdx.x * 256 + threadIdx.x;   // each thread: 4 floats
    float4 v = reinterpret_cast<const float4*>(x)[idx];
    ushort4 o;
    o.x = f2b(v.x); o.y = f2b(v.y); o.z = f2b(v.z); o.w = f2b(v.w);
    reinterpret_cast<ushort4*>(xb)[idx] = o;
}

// in: (E, R, Cd) fp32 row-major  ->  out: (E, Cd, R) bf16
__global__ __launch_bounds__(256) void transpose_cvt_kernel(const float* __restrict__ in,
                                                            u16* __restrict__ out,
                                                            int R, int Cd) {
    __shared__ float tile[32][33];
    int e = blockIdx.z;
    const float* ip = in + (size_t)e * R * Cd;
    u16* op = out + (size_t)e * R * Cd;
    int c0 = blockIdx.x * 32, r0 = blockIdx.y * 32;
    int tx = threadIdx.x & 31;
    int ty = threadIdx.x >> 5;   // 0..7
#pragma unroll
    for (int k = 0; k < 4; k++)
        tile[ty + 8 * k][tx] = ip[(size_t)(r0 + ty + 8 * k) * Cd + c0 + tx];
    __syncthreads();
#pragma unroll
    for (int k = 0; k < 4; k++)
        op[(size_t)(c0 + ty + 8 * k) * R + r0 + tx] = f2b(tile[tx][ty + 8 * k]);
}

// ---------------- 256x256 ring-4, two-phase-per-slice GEMM core ----------------
// A: M x K bf16 row-major (k-contig). Bt: N x K bf16 row-major (k-contig).
// 512 threads = 8 waves (2M x 4N), per-wave output 128x64 = acc[8][4] 16x16 frags.
// LDS per operand: ring of 4 slots of [256 rows][32 k] bf16 (16 KiB each),
// slot for slice s = s&3. Each slice = 2 phases (M-half quadrants, 16 MFMA each):
//   phase: {ds_read frags, issue 2 global_load_lds} -> s_barrier -> lgkmcnt(0)
//          -> setprio(1) 16xMFMA setprio(0) -> [vmcnt(8) at slice end] -> s_barrier
// vmcnt is counted (8 = slices s+2,s+3 in flight), NEVER 0 in the main loop.
// Safety: STAGE targets slot (s+3)&3 == (s-1)&3; every wave's reads of slot s-1
// completed before iter s-1's final barrier (lgkmcnt(0) precedes its MFMAs),
// and STAGE is issued only after that barrier.
// Swizzle (involution, both sides): byte ^= ((byte>>7)&3)<<4 within a slot.
// global_load_lds writes linearly; per-lane GLOBAL source is inverse-swizzled,
// ds_read uses the swizzled address (rule 21). Measured 0 bank conflicts.
template<int K>
__device__ inline void gemm_core(const u16* __restrict__ A, const u16* __restrict__ Bt,
                                 u16* ldsA, u16* ldsB, int m0, int n0, v4f (&acc)[8][4]) {
    constexpr int NS = K / 32;
    const int t = threadIdx.x, w = t >> 6, l = t & 63;
    const int wm = w >> 2, wn = w & 3;

    // staging precompute: linear LDS dest f -> logical g -> global (row, col)
    const u16* asrc[2]; const u16* bsrc[2]; int adst[2];
#pragma unroll
    for (int u = 0; u < 2; ++u) {
        int f = u * 8192 + w * 1024 + l * 16;        // dest byte offset in slot
        int g = f ^ (((f >> 7) & 3) << 4);           // logical byte offset
        int row = g >> 6, col = (g >> 1) & 31;       // 64B rows, elem col (x8 aligned)
        asrc[u] = A  + (size_t)(m0 + row) * K + col;
        bsrc[u] = Bt + (size_t)(n0 + row) * K + col;
        adst[u] = u * 4096 + w * 512;                // wave-uniform elem offset
    }

    // fragment LDS element offsets (swizzled), constant through the loop
    const int lr = l & 15, lk = l >> 4;
    int aoffE[8], boffE[4];
#pragma unroll
    for (int i = 0; i < 8; ++i) {
        int g = (wm * 128 + i * 16 + lr) * 64 + lk * 16;
        aoffE[i] = (g ^ (((g >> 7) & 3) << 4)) >> 1;
    }
#pragma unroll
    for (int j = 0; j < 4; ++j) {
        int g = (wn * 64 + j * 16 + lr) * 64 + lk * 16;
        boffE[j] = (g ^ (((g >> 7) & 3) << 4)) >> 1;
    }

    auto STAGE_A = [&](int ks) {
        u16* la = ldsA + (ks & 3) * 8192;
        int ko = ks * 32;
        gload16(asrc[0] + ko, la + adst[0]);
        gload16(asrc[1] + ko, la + adst[1]);
    };
    auto STAGE_B = [&](int ks) {
        u16* lb = ldsB + (ks & 3) * 8192;
        int ko = ks * 32;
        gload16(bsrc[0] + ko, lb + adst[0]);
        gload16(bsrc[1] + ko, lb + adst[1]);
    };

#pragma unroll
    for (int i = 0; i < 8; ++i)
#pragma unroll
        for (int j = 0; j < 4; ++j) acc[i][j] = (v4f){0.f, 0.f, 0.f, 0.f};

    // prologue: slices 0,1,2 in flight; land slice 0 (12 issued -> keep 8 newest)
    STAGE_A(0); STAGE_B(0); STAGE_A(1); STAGE_B(1); STAGE_A(2); STAGE_B(2);
    asm volatile("s_waitcnt vmcnt(8)" ::: "memory");
    __builtin_amdgcn_s_barrier();

    for (int s = 0; s < NS; ++s) {
        const u16* as = ldsA + (s & 3) * 8192;
        const u16* bs = ldsB + (s & 3) * 8192;
        v8bf af[8], bfr[4];
        // ---------------- phase 1: M-lo quadrant ----------------
#pragma unroll
        for (int i = 0; i < 4; ++i) af[i] = *(const v8bf*)(as + aoffE[i]);
#pragma unroll
        for (int j = 0; j < 4; ++j) bfr[j] = *(const v8bf*)(bs + boffE[j]);
        if (s < NS - 3) STAGE_A(s + 3);
        __builtin_amdgcn_s_barrier();
        asm volatile("s_waitcnt lgkmcnt(0)" ::: "memory");
        __builtin_amdgcn_s_setprio(1);
#pragma unroll
        for (int i = 0; i < 4; ++i)
#pragma unroll
            for (int j = 0; j < 4; ++j)
                acc[i][j] = __builtin_amdgcn_mfma_f32_16x16x32_bf16(af[i], bfr[j], acc[i][j], 0, 0, 0);
        __builtin_amdgcn_s_setprio(0);
        __builtin_amdgcn_s_barrier();
        // ---------------- phase 2: M-hi quadrant ----------------
#pragma unroll
        for (int i = 4; i < 8; ++i) af[i] = *(const v8bf*)(as + aoffE[i]);
        if (s < NS - 3) STAGE_B(s + 3);
        __builtin_amdgcn_s_barrier();
        asm volatile("s_waitcnt lgkmcnt(0)" ::: "memory");
        __builtin_amdgcn_s_setprio(1);
#pragma unroll
        for (int i = 4; i < 8; ++i)
#pragma unroll
            for (int j = 0; j < 4; ++j)
                acc[i][j] = __builtin_amdgcn_mfma_f32_16x16x32_bf16(af[i], bfr[j], acc[i][j], 0, 0, 0);
        __builtin_amdgcn_s_setprio(0);
        // counted end-of-slice drains: slice s+1 must have landed before barrier.
        if (s < NS - 3)       asm volatile("s_waitcnt vmcnt(8)" ::: "memory");
        else if (s == NS - 3) asm volatile("s_waitcnt vmcnt(4)" ::: "memory");
        else if (s == NS - 2) asm volatile("s_waitcnt vmcnt(0)" ::: "memory");
        if (s < NS - 1) __builtin_amdgcn_s_barrier();
    }
}

// ---------------- GEMM1: h[e] = gelu(x @ w1[e]), bf16 out ----------------
// 1-D grid. Batched (nE==8): e = id&7 -> each expert pinned to one XCD
// (dispatch round-robins blockIdx across the 8 XCDs); within an expert,
// n varies fastest so the 4MB B-panel stays L2-resident across m-blocks.
__global__ __launch_bounds__(512, 2) void gemm1_kernel(const u16* __restrict__ A,
                                                       const u16* __restrict__ w1T,
                                                       u16* __restrict__ H,
                                                       int e_base, int nE, size_t h_stride) {
    __shared__ __align__(16) u16 lds[65536];   // 128 KiB: A ring 64K + B ring 64K
    int id = blockIdx.x;
    int e, j;
    if (nE == E_DIM) { e = id & 7; j = id >> 3; }
    else             { e = e_base; j = id; }
    int n0 = (j & 7) * 256;          // NBN = I/256 = 8
    int m0 = (j >> 3) * 256;
    const u16* Bt = w1T + (size_t)e * I_DIM * C_DIM;
    u16* Hp = H + (size_t)(e - e_base) * h_stride;

    v4f acc[8][4];
    gemm_core<C_DIM>(A, Bt, lds, lds + 32768, m0, n0, acc);

    int l = threadIdx.x & 63, w = threadIdx.x >> 6;
    int wm = w >> 2, wn = w & 3;
    int lr4 = (l >> 4) * 4, lc = l & 15;     // C/D: row=(lane>>4)*4+reg, col=lane&15
#pragma unroll
    for (int i = 0; i < 8; ++i) {
        int mg = m0 + wm * 128 + i * 16 + lr4;
#pragma unroll
        for (int j2 = 0; j2 < 4; ++j2) {
            int ng = n0 + wn * 64 + j2 * 16 + lc;
#pragma unroll
            for (int r = 0; r < 4; ++r)
                Hp[(size_t)(mg + r) * I_DIM + ng] = f2b(fast_gelu(acc[i][j2][r]));
        }
    }
}

// ---------------- GEMM2: eo[:,e,:] = h[e] @ w2[e], fp32 strided out ----------------
__global__ __launch_bounds__(512, 2) void gemm2_kernel(const u16* __restrict__ H,
                                                       const u16* __restrict__ w2T,
                                                       float* __restrict__ EO,
                                                       int e_base, int nE, size_t h_stride) {
    __shared__ __align__(16) u16 lds[65536];
    int id = blockIdx.x;
    int e, j;
    if (nE == E_DIM) { e = id & 7; j = id >> 3; }
    else             { e = e_base; j = id; }
    int n0 = (j & 3) * 256;          // NBN = C/256 = 4
    int m0 = (j >> 2) * 256;
    const u16* A  = H + (size_t)(e - e_base) * h_stride;
    const u16* Bt = w2T + (size_t)e * C_DIM * I_DIM;

    v4f acc[8][4];
    gemm_core<I_DIM>(A, Bt, lds, lds + 32768, m0, n0, acc);

    int l = threadIdx.x & 63, w = threadIdx.x >> 6;
    int wm = w >> 2, wn = w & 3;
    int lr4 = (l >> 4) * 4, lc = l & 15;
#pragma unroll
    for (int i = 0; i < 8; ++i) {
        int mg = m0 + wm * 128 + i * 16 + lr4;
#pragma unroll
        for (int j2 = 0; j2 < 4; ++j2) {
            int ng = n0 + wn * 64 + j2 * 16 + lc;
#pragma unroll
            for (int r = 0; r < 4; ++r)
                EO[((size_t)(mg + r) * E_DIM + e) * C_DIM + ng] = acc[i][j2][r];
        }
    }
}

// ---------------- combine: agg[m][c] = sum_e r[m][e] * eo[m][e][c] ----------------
__global__ __launch_bounds__(256) void combine_kernel(const float* __restrict__ EO,
                                                      const float* __restrict__ Rw,
                                                      float* __restrict__ agg) {
    int idx = blockIdx.x * 256 + threadIdx.x;
    int m = idx >> 8, cq = idx & 255;           // 256 float4 per row
    const float4* eo4 = reinterpret_cast<const float4*>(EO);
    float4 s = make_float4(0.f, 0.f, 0.f, 0.f);
#pragma unroll
    for (int e = 0; e < E_DIM; e++) {
        float r = Rw[m * E_DIM + e];
        float4 v = eo4[((size_t)m * E_DIM + e) * 256 + cq];
        s.x += r * v.x; s.y += r * v.y; s.z += r * v.z; s.w += r * v.w;
    }
    reinterpret_cast<float4*>(agg)[(size_t)m * 256 + cq] = s;
}

extern "C" void kernel_launch(void* const* d_in, const int* in_sizes, int n_in,
                              void* d_out, int out_size, void* d_ws, size_t ws_size,
                              hipStream_t stream) {
    const float* x  = (const float*)d_in[0];
    const float* rw = (const float*)d_in[1];
    const float* w1 = (const float*)d_in[2];
    const float* w2 = (const float*)d_in[3];

    float* agg = (float*)d_out;
    float* EO  = agg + (size_t)M_TOT * C_DIM;   // experts_out region

    // workspace layout (bf16 elements)
    u16* xb  = (u16*)d_ws;                              // 8192*1024
    u16* w1T = xb  + (size_t)M_TOT * C_DIM;             // 8*2048*1024  [e][i][c]
    u16* w2T = w1T + (size_t)E_DIM * I_DIM * C_DIM;     // 8*1024*2048  [e][c][i]
    u16* h   = w2T + (size_t)E_DIM * C_DIM * I_DIM;     // h region

    size_t elems_before_h = (size_t)M_TOT * C_DIM + 2 * (size_t)E_DIM * I_DIM * C_DIM;
    size_t h_per_expert   = (size_t)M_TOT * I_DIM;
    bool batched = ws_size >= (elems_before_h + (size_t)E_DIM * h_per_expert) * sizeof(u16);

    cvt_x_kernel<<<(M_TOT * C_DIM) / 1024, 256, 0, stream>>>(x, xb);
    transpose_cvt_kernel<<<dim3(I_DIM / 32, C_DIM / 32, E_DIM), 256, 0, stream>>>(w1, w1T, C_DIM, I_DIM);
    transpose_cvt_kernel<<<dim3(C_DIM / 32, I_DIM / 32, E_DIM), 256, 0, stream>>>(w2, w2T, I_DIM, C_DIM);

    if (batched) {
        gemm1_kernel<<<E_DIM * 8 * 32, 512, 0, stream>>>(xb, w1T, h, 0, E_DIM, h_per_expert);
        gemm2_kernel<<<E_DIM * 4 * 32, 512, 0, stream>>>(h, w2T, EO, 0, E_DIM, h_per_expert);
    } else {
        for (int e = 0; e < E_DIM; e++) {
            gemm1_kernel<<<8 * 32, 512, 0, stream>>>(xb, w1T, h, e, 1, 0);
            gemm2_kernel<<<4 * 32, 512, 0, stream>>>(h, w2T, EO, e, 1, 0);
        }
    }

    combine_kernel<<<M_TOT, 256, 0, stream>>>(EO, rw, agg);
}

// Round 3
// 981.713 us; speedup vs baseline: 1.0681x; 1.0240x over previous
//
#include <hip/hip_runtime.h>
#include <hip/hip_bf16.h>

// Problem constants: B=4, T=2048, E=8, C=1024, I=2048. M = B*T = 8192.
// Outputs: agg [8192,1024] fp32, experts_out [8192,8,1024] fp32, concat in d_out.

typedef unsigned short u16;
typedef __bf16 v8bf __attribute__((ext_vector_type(8)));
typedef float  v4f  __attribute__((ext_vector_type(4)));

#define M_TOT 8192
#define E_DIM 8
#define C_DIM 1024
#define I_DIM 2048

__device__ inline u16 f2b(float f) {
    __hip_bfloat16 h = __float2bfloat16(f);
    return *reinterpret_cast<u16*>(&h);
}

// tanh-form GELU: max |diff vs exact-erf gelu| ~3e-3, NaN-safe at |x| large.
__device__ inline float fast_gelu(float x) {
    float x2 = x * x;
    float z  = x * fmaf(0.0356774081f, x2, 0.7978845608f);
    float u  = __expf(2.0f * z);
    float th = fmaf(-2.0f, __builtin_amdgcn_rcpf(u + 1.0f), 1.0f);
    return 0.5f * x * (1.0f + th);
}

// async global->LDS, 16B per lane; LDS dest = wave-uniform base + lane*16
__device__ inline void gload16(const u16* g, u16* l) {
    __builtin_amdgcn_global_load_lds(
        (const __attribute__((address_space(1))) void*)g,
        (__attribute__((address_space(3))) void*)l,
        16, 0, 0);
}

// ---------------- pass 0: conversions ----------------

__global__ __launch_bounds__(256) void cvt_x_kernel(const float* __restrict__ x,
                                                    u16* __restrict__ xb) {
    int idx = blockIdx.x * 256 + threadIdx.x;   // each thread: 4 floats
    float4 v = reinterpret_cast<const float4*>(x)[idx];
    ushort4 o;
    o.x = f2b(v.x); o.y = f2b(v.y); o.z = f2b(v.z); o.w = f2b(v.w);
    reinterpret_cast<ushort4*>(xb)[idx] = o;
}

// in: (E, R, Cd) fp32 row-major  ->  out: (E, Cd, R) bf16
__global__ __launch_bounds__(256) void transpose_cvt_kernel(const float* __restrict__ in,
                                                            u16* __restrict__ out,
                                                            int R, int Cd) {
    __shared__ float tile[32][33];
    int e = blockIdx.z;
    const float* ip = in + (size_t)e * R * Cd;
    u16* op = out + (size_t)e * R * Cd;
    int c0 = blockIdx.x * 32, r0 = blockIdx.y * 32;
    int tx = threadIdx.x & 31;
    int ty = threadIdx.x >> 5;   // 0..7
#pragma unroll
    for (int k = 0; k < 4; k++)
        tile[ty + 8 * k][tx] = ip[(size_t)(r0 + ty + 8 * k) * Cd + c0 + tx];
    __syncthreads();
#pragma unroll
    for (int k = 0; k < 4; k++)
        op[(size_t)(c0 + ty + 8 * k) * R + r0 + tx] = f2b(tile[tx][ty + 8 * k]);
}

// ---------------- 256x256 K-tile(64) 4-phase pinned-schedule GEMM core ----------------
// A: M x K bf16 row-major (k-contig). Bt: N x K bf16 row-major (k-contig).
// 512 threads = 8 waves (2M x 4N), per-wave output 128x64 = acc[8][4] 16x16 frags.
// LDS per operand: 4 slots of [256 rows][32 k] bf16 (16 KiB each) = ping/pong pair
// of 64-k K-tile buffers (slot s&3). Per K-tile t (slices 2t,2t+1): 4 phases over
// C-quadrants (m0n0, m0n1, m1n1, m1n0), 16 MFMA each, ds_reads 12/4/8/0 (B frags
// held live across phases). Phase skeleton (m201 template, rule-18 pinned):
//   {ds_reads, 2 gloads} -> s_barrier -> lgkmcnt(0) -> sched_barrier(0)
//   -> setprio(1) 16xMFMA setprio(0) -> sched_barrier(0) -> s_barrier
// Staging: tile t+1's 8 gloads spread over iter t's phases; one vmcnt(0) at
// iter end (youngest load >=3 phases old -> nominally free). Hazard: stage
// targets = tile t-1's slots; their reads drained at iter t-1's phase lgkmcnt(0)s,
// before its closing barrier, which precedes every iter-t stage issue.
// Swizzle (involution, both sides): byte ^= ((byte>>7)&3)<<4 within a slot.
// global_load_lds writes linearly; per-lane GLOBAL source is inverse-swizzled,
// ds_read uses the swizzled address (rule 21). Measured 0 bank conflicts.
#define PH_PRE  __builtin_amdgcn_s_barrier();                            \
                asm volatile("s_waitcnt lgkmcnt(0)" ::: "memory");       \
                __builtin_amdgcn_sched_barrier(0);                       \
                __builtin_amdgcn_s_setprio(1);
#define PH_POST __builtin_amdgcn_s_setprio(0);                           \
                __builtin_amdgcn_sched_barrier(0);                       \
                __builtin_amdgcn_s_barrier();

template<int K>
__device__ inline void gemm_core(const u16* __restrict__ A, const u16* __restrict__ Bt,
                                 u16* ldsA, u16* ldsB, int m0, int n0, v4f (&acc)[8][4]) {
    constexpr int NT = K / 64;   // K-tiles (2 LDS slices each)
    const int t0 = threadIdx.x, w = t0 >> 6, l = t0 & 63;
    const int wm = w >> 2, wn = w & 3;

    // staging precompute: linear LDS dest f -> logical g -> global (row, col)
    const u16* asrc[2]; const u16* bsrc[2]; int adst[2];
#pragma unroll
    for (int u = 0; u < 2; ++u) {
        int f = u * 8192 + w * 1024 + l * 16;        // dest byte offset in slot
        int g = f ^ (((f >> 7) & 3) << 4);           // logical byte offset
        int row = g >> 6, col = (g >> 1) & 31;       // 64B rows, elem col (x8 aligned)
        asrc[u] = A  + (size_t)(m0 + row) * K + col;
        bsrc[u] = Bt + (size_t)(n0 + row) * K + col;
        adst[u] = u * 4096 + w * 512;                // wave-uniform elem offset
    }

    // fragment LDS element offsets (swizzled), constant through the loop
    const int lr = l & 15, lk = l >> 4;
    int aoffE[8], boffE[4];
#pragma unroll
    for (int i = 0; i < 8; ++i) {
        int g = (wm * 128 + i * 16 + lr) * 64 + lk * 16;
        aoffE[i] = (g ^ (((g >> 7) & 3) << 4)) >> 1;
    }
#pragma unroll
    for (int j = 0; j < 4; ++j) {
        int g = (wn * 64 + j * 16 + lr) * 64 + lk * 16;
        boffE[j] = (g ^ (((g >> 7) & 3) << 4)) >> 1;
    }

    auto STAGE_A = [&](int ks) {
        u16* la = ldsA + (ks & 3) * 8192;
        int ko = ks * 32;
        gload16(asrc[0] + ko, la + adst[0]);
        gload16(asrc[1] + ko, la + adst[1]);
    };
    auto STAGE_B = [&](int ks) {
        u16* lb = ldsB + (ks & 3) * 8192;
        int ko = ks * 32;
        gload16(bsrc[0] + ko, lb + adst[0]);
        gload16(bsrc[1] + ko, lb + adst[1]);
    };

#pragma unroll
    for (int i = 0; i < 8; ++i)
#pragma unroll
        for (int j = 0; j < 4; ++j) acc[i][j] = (v4f){0.f, 0.f, 0.f, 0.f};

    // prologue: stage K-tile 0 (slices 0,1); full drain before first reads
    STAGE_A(0); STAGE_A(1); STAGE_B(0); STAGE_B(1);
    asm volatile("s_waitcnt vmcnt(0)" ::: "memory");
    __builtin_amdgcn_s_barrier();

    for (int t = 0; t < NT; ++t) {
        const u16* a0 = ldsA + ((t & 1) * 2) * 8192;   // ksub0 slice
        const u16* a1 = a0 + 8192;                     // ksub1 slice
        const u16* b0 = ldsB + ((t & 1) * 2) * 8192;
        const u16* b1 = b0 + 8192;
        const bool pf = (t < NT - 1);
        v8bf af0[4], af1[4];          // current m-half fragments, both ksubs
        v8bf b00[2], b01[2];          // n-lo frags, ksub0/ksub1 (live all 4 phases)
        v8bf b10[2], b11[2];          // n-hi frags

        // ---- phase 1: m-lo x n-lo (12 reads) ----
#pragma unroll
        for (int i = 0; i < 4; ++i) {
            af0[i] = *(const v8bf*)(a0 + aoffE[i]);
            af1[i] = *(const v8bf*)(a1 + aoffE[i]);
        }
#pragma unroll
        for (int j = 0; j < 2; ++j) {
            b00[j] = *(const v8bf*)(b0 + boffE[j]);
            b01[j] = *(const v8bf*)(b1 + boffE[j]);
        }
        if (pf) STAGE_A(2 * t + 2);
        PH_PRE
#pragma unroll
        for (int i = 0; i < 4; ++i)
#pragma unroll
            for (int j = 0; j < 2; ++j) {
                acc[i][j] = __builtin_amdgcn_mfma_f32_16x16x32_bf16(af0[i], b00[j], acc[i][j], 0, 0, 0);
                acc[i][j] = __builtin_amdgcn_mfma_f32_16x16x32_bf16(af1[i], b01[j], acc[i][j], 0, 0, 0);
            }
        PH_POST

        // ---- phase 2: m-lo x n-hi (4 reads) ----
#pragma unroll
        for (int j = 0; j < 2; ++j) {
            b10[j] = *(const v8bf*)(b0 + boffE[2 + j]);
            b11[j] = *(const v8bf*)(b1 + boffE[2 + j]);
        }
        if (pf) STAGE_A(2 * t + 3);
        PH_PRE
#pragma unroll
        for (int i = 0; i < 4; ++i)
#pragma unroll
            for (int j = 0; j < 2; ++j) {
                acc[i][2 + j] = __builtin_amdgcn_mfma_f32_16x16x32_bf16(af0[i], b10[j], acc[i][2 + j], 0, 0, 0);
                acc[i][2 + j] = __builtin_amdgcn_mfma_f32_16x16x32_bf16(af1[i], b11[j], acc[i][2 + j], 0, 0, 0);
            }
        PH_POST

        // ---- phase 3: m-hi x n-hi (8 reads) ----
#pragma unroll
        for (int i = 0; i < 4; ++i) {
            af0[i] = *(const v8bf*)(a0 + aoffE[4 + i]);
            af1[i] = *(const v8bf*)(a1 + aoffE[4 + i]);
        }
        if (pf) STAGE_B(2 * t + 2);
        PH_PRE
#pragma unroll
        for (int i = 0; i < 4; ++i)
#pragma unroll
            for (int j = 0; j < 2; ++j) {
                acc[4 + i][2 + j] = __builtin_amdgcn_mfma_f32_16x16x32_bf16(af0[i], b10[j], acc[4 + i][2 + j], 0, 0, 0);
                acc[4 + i][2 + j] = __builtin_amdgcn_mfma_f32_16x16x32_bf16(af1[i], b11[j], acc[4 + i][2 + j], 0, 0, 0);
            }
        PH_POST

        // ---- phase 4: m-hi x n-lo (0 reads) ----
        if (pf) STAGE_B(2 * t + 3);
        PH_PRE
#pragma unroll
        for (int i = 0; i < 4; ++i)
#pragma unroll
            for (int j = 0; j < 2; ++j) {
                acc[4 + i][j] = __builtin_amdgcn_mfma_f32_16x16x32_bf16(af0[i], b00[j], acc[4 + i][j], 0, 0, 0);
                acc[4 + i][j] = __builtin_amdgcn_mfma_f32_16x16x32_bf16(af1[i], b01[j], acc[4 + i][j], 0, 0, 0);
            }
        __builtin_amdgcn_s_setprio(0);
        __builtin_amdgcn_sched_barrier(0);
        if (pf) {
            // tile t+1 fully landed before iter t+1 phase-1 ds_reads; youngest
            // load is >=3 phases old here, so this drain is nominally free.
            asm volatile("s_waitcnt vmcnt(0)" ::: "memory");
            __builtin_amdgcn_s_barrier();
        }
    }
}

// ---------------- GEMM1: h[e] = gelu(x @ w1[e]), bf16 out ----------------
// 1-D grid. Batched (nE==8): e = id&7 -> each expert pinned to one XCD;
// within an expert, n varies fastest so the B-panel stays L2-resident.
__global__ __launch_bounds__(512, 2) void gemm1_kernel(const u16* __restrict__ A,
                                                       const u16* __restrict__ w1T,
                                                       u16* __restrict__ H,
                                                       int e_base, int nE, size_t h_stride) {
    __shared__ __align__(16) u16 lds[65536];   // 128 KiB: A slots 64K + B slots 64K
    int id = blockIdx.x;
    int e, j;
    if (nE == E_DIM) { e = id & 7; j = id >> 3; }
    else             { e = e_base; j = id; }
    int n0 = (j & 7) * 256;          // NBN = I/256 = 8
    int m0 = (j >> 3) * 256;
    const u16* Bt = w1T + (size_t)e * I_DIM * C_DIM;
    u16* Hp = H + (size_t)(e - e_base) * h_stride;

    v4f acc[8][4];
    gemm_core<C_DIM>(A, Bt, lds, lds + 32768, m0, n0, acc);

    int l = threadIdx.x & 63, w = threadIdx.x >> 6;
    int wm = w >> 2, wn = w & 3;
    int lr4 = (l >> 4) * 4, lc = l & 15;     // C/D: row=(lane>>4)*4+reg, col=lane&15
#pragma unroll
    for (int i = 0; i < 8; ++i) {
        int mg = m0 + wm * 128 + i * 16 + lr4;
#pragma unroll
        for (int j2 = 0; j2 < 4; ++j2) {
            int ng = n0 + wn * 64 + j2 * 16 + lc;
#pragma unroll
            for (int r = 0; r < 4; ++r)
                Hp[(size_t)(mg + r) * I_DIM + ng] = f2b(fast_gelu(acc[i][j2][r]));
        }
    }
}

// ---------------- GEMM2: eo[:,e,:] = h[e] @ w2[e], fp32 strided out ----------------
__global__ __launch_bounds__(512, 2) void gemm2_kernel(const u16* __restrict__ H,
                                                       const u16* __restrict__ w2T,
                                                       float* __restrict__ EO,
                                                       int e_base, int nE, size_t h_stride) {
    __shared__ __align__(16) u16 lds[65536];
    int id = blockIdx.x;
    int e, j;
    if (nE == E_DIM) { e = id & 7; j = id >> 3; }
    else             { e = e_base; j = id; }
    int n0 = (j & 3) * 256;          // NBN = C/256 = 4
    int m0 = (j >> 2) * 256;
    const u16* A  = H + (size_t)(e - e_base) * h_stride;
    const u16* Bt = w2T + (size_t)e * C_DIM * I_DIM;

    v4f acc[8][4];
    gemm_core<I_DIM>(A, Bt, lds, lds + 32768, m0, n0, acc);

    int l = threadIdx.x & 63, w = threadIdx.x >> 6;
    int wm = w >> 2, wn = w & 3;
    int lr4 = (l >> 4) * 4, lc = l & 15;
#pragma unroll
    for (int i = 0; i < 8; ++i) {
        int mg = m0 + wm * 128 + i * 16 + lr4;
#pragma unroll
        for (int j2 = 0; j2 < 4; ++j2) {
            int ng = n0 + wn * 64 + j2 * 16 + lc;
#pragma unroll
            for (int r = 0; r < 4; ++r)
                EO[((size_t)(mg + r) * E_DIM + e) * C_DIM + ng] = acc[i][j2][r];
        }
    }
}

// ---------------- combine: agg[m][c] = sum_e r[m][e] * eo[m][e][c] ----------------
__global__ __launch_bounds__(256) void combine_kernel(const float* __restrict__ EO,
                                                      const float* __restrict__ Rw,
                                                      float* __restrict__ agg) {
    int idx = blockIdx.x * 256 + threadIdx.x;
    int m = idx >> 8, cq = idx & 255;           // 256 float4 per row
    const float4* eo4 = reinterpret_cast<const float4*>(EO);
    float4 s = make_float4(0.f, 0.f, 0.f, 0.f);
#pragma unroll
    for (int e = 0; e < E_DIM; e++) {
        float r = Rw[m * E_DIM + e];
        float4 v = eo4[((size_t)m * E_DIM + e) * 256 + cq];
        s.x += r * v.x; s.y += r * v.y; s.z += r * v.z; s.w += r * v.w;
    }
    reinterpret_cast<float4*>(agg)[(size_t)m * 256 + cq] = s;
}

extern "C" void kernel_launch(void* const* d_in, const int* in_sizes, int n_in,
                              void* d_out, int out_size, void* d_ws, size_t ws_size,
                              hipStream_t stream) {
    const float* x  = (const float*)d_in[0];
    const float* rw = (const float*)d_in[1];
    const float* w1 = (const float*)d_in[2];
    const float* w2 = (const float*)d_in[3];

    float* agg = (float*)d_out;
    float* EO  = agg + (size_t)M_TOT * C_DIM;   // experts_out region

    // workspace layout (bf16 elements)
    u16* xb  = (u16*)d_ws;                              // 8192*1024
    u16* w1T = xb  + (size_t)M_TOT * C_DIM;             // 8*2048*1024  [e][i][c]
    u16* w2T = w1T + (size_t)E_DIM * I_DIM * C_DIM;     // 8*1024*2048  [e][c][i]
    u16* h   = w2T + (size_t)E_DIM * C_DIM * I_DIM;     // h region

    size_t elems_before_h = (size_t)M_TOT * C_DIM + 2 * (size_t)E_DIM * I_DIM * C_DIM;
    size_t h_per_expert   = (size_t)M_TOT * I_DIM;
    bool batched = ws_size >= (elems_before_h + (size_t)E_DIM * h_per_expert) * sizeof(u16);

    cvt_x_kernel<<<(M_TOT * C_DIM) / 1024, 256, 0, stream>>>(x, xb);
    transpose_cvt_kernel<<<dim3(I_DIM / 32, C_DIM / 32, E_DIM), 256, 0, stream>>>(w1, w1T, C_DIM, I_DIM);
    transpose_cvt_kernel<<<dim3(C_DIM / 32, I_DIM / 32, E_DIM), 256, 0, stream>>>(w2, w2T, I_DIM, C_DIM);

    if (batched) {
        gemm1_kernel<<<E_DIM * 8 * 32, 512, 0, stream>>>(xb, w1T, h, 0, E_DIM, h_per_expert);
        gemm2_kernel<<<E_DIM * 4 * 32, 512, 0, stream>>>(h, w2T, EO, 0, E_DIM, h_per_expert);
    } else {
        for (int e = 0; e < E_DIM; e++) {
            gemm1_kernel<<<8 * 32, 512, 0, stream>>>(xb, w1T, h, e, 1, 0);
            gemm2_kernel<<<4 * 32, 512, 0, stream>>>(h, w2T, EO, e, 1, 0);
        }
    }

    combine_kernel<<<M_TOT, 256, 0, stream>>>(EO, rw, agg);
}